// Round 15
// baseline (90.844 us; speedup 1.0000x reference)
//
#include <hip/hip_runtime.h>
#include <hip/hip_bf16.h>
#include <math.h>
#include <stdint.h>

#define BHN    64
#define SEQ    4096
#define DIM    64
#define NCHUNK 16
#define CHUNK  (SEQ / NCHUNK)        // 256 rows per pass-1 block
#define KSTEP  32                    // s-rows per tile
#define NIT    (CHUNK / KSTEP)       // 8 tiles, ALL resident in LDS
#define KVF    (128 * DIM)           // 8192 floats of kv per head
#define STRIDE_C ((size_t)BHN * KVF + (size_t)BHN * 128)   // 532480 floats
#define KSBASE ((size_t)BHN * KVF)   // 524288
#define FRAGH  10240                 // bf16 per head: 5 t * 4 ks * 64 lanes * 8 j
#define LPADT  40                    // transposed tile row pitch (ushorts)

typedef __bf16 bf16x8v __attribute__((ext_vector_type(8)));
typedef float  f32x4v  __attribute__((ext_vector_type(4)));

__device__ inline f32x4v mfma16(bf16x8v a, bf16x8v b, f32x4v c) {
    return __builtin_amdgcn_mfma_f32_16x16x32_bf16(a, b, c, 0, 0, 0);
}

__device__ inline unsigned pk2(float a, float b) {
    __hip_bfloat162 t(__float2bfloat16(a), __float2bfloat16(b));
    return *(unsigned*)&t;
}

// Raw workgroup barrier WITHOUT the compiler's vmcnt(0) drain.
__device__ __forceinline__ void barrier_noflush() {
    asm volatile("s_waitcnt lgkmcnt(0)" ::: "memory");
    __builtin_amdgcn_s_barrier();
    asm volatile("" ::: "memory");
}

// Async global->LDS, 16B/lane, dest = wave-uniform base + lane*16.
__device__ __forceinline__ void gload16(const float* g, const float* lds_base) {
    __builtin_amdgcn_global_load_lds(
        (const __attribute__((address_space(1))) void*)(uintptr_t)g,
        (__attribute__((address_space(3)))  void*)(uintptr_t)lds_base,
        16, 0, 0);
}

// ------- Pass 1 v4: FULL-DEPTH async pipeline -------
// All 8 raw K/V tiles (128 KB) get distinct LDS buffers; every gload_lds of
// the block is issued before the first wait. Consumption uses literal
// descending vmcnt (14,12,...,0) — the entire read volume stays in flight.
template<int USE_ATOMIC>
__global__ __launch_bounds__(512) void cosformer_kv_mfma(
    const float* __restrict__ K, const float* __restrict__ V,
    float* __restrict__ part)
{
    __shared__ float  rawK[NIT][KSTEP][DIM];   // 64 KB
    __shared__ float  rawV[NIT][KSTEP][DIM];   // 64 KB
    __shared__ ushort ktc[DIM][LPADT];         // relu(K)*cos, [d][s] bf16
    __shared__ ushort kts[DIM][LPADT];         // relu(K)*sin
    __shared__ ushort vtt[DIM][LPADT];         // V transposed

    const int bh    = blockIdx.x / NCHUNK;
    const int chunk = blockIdx.x % NCHUNK;
    const int row0  = chunk * CHUNK;
    const float* Kb = K + (size_t)bh * SEQ * DIM;
    const float* Vb = V + (size_t)bh * SEQ * DIM;

    const int tid  = threadIdx.x;
    const int lane = tid & 63;
    const int w    = tid >> 6;           // 0..7
    const int g2    = (tid >> 4) & 15;   // transform: row-pair 0..15
    const int dq    = (tid & 15) * 4;    // transform: d-block of 4
    const int kvsel = tid >> 8;          // 0 = K threads, 1 = V threads
    const int frow = lane & 15;
    const int kgrp = lane >> 4;
    const int d0   = (w & 3) * 16 + frow;

    f32x4v acc[5];
    #pragma unroll
    for (int t = 0; t < 5; ++t) acc[t] = (f32x4v){0.f, 0.f, 0.f, 0.f};

    bf16x8v onef;
    #pragma unroll
    for (int j = 0; j < 8; ++j) onef[j] = (frow == 0) ? (__bf16)1.0f : (__bf16)0.0f;

    // ---- issue the ENTIRE block read volume (16 gloads/wave), zero waits ----
    #pragma unroll
    for (int t = 0; t < NIT; ++t) {
        const size_t go = (size_t)(row0 + t * KSTEP) * DIM + w * 256 + lane * 4;
        gload16(Kb + go, &rawK[t][w * 4][0]);
        gload16(Vb + go, &rawV[t][w * 4][0]);
    }

    auto TRANSFORM = [&](int it) {
        const int r = 2 * g2;
        if (kvsel == 0) {
            float4 k0 = *(const float4*)&rawK[it][r][dq];
            float4 k1 = *(const float4*)&rawK[it][r + 1][dq];
            const int l0 = row0 + it * KSTEP + r;
            const float CC = 1.5707963267948966f / (float)SEQ;
            float s0v, c0, s1v, c1;
            __sincosf(CC * (float)(l0 + 1), &s0v, &c0);
            __sincosf(CC * (float)(l0 + 2), &s1v, &c1);
            float a0[4] = {k0.x, k0.y, k0.z, k0.w};
            float a1[4] = {k1.x, k1.y, k1.z, k1.w};
            #pragma unroll
            for (int i = 0; i < 4; ++i) {
                const int d = dq + i;
                const int c = g2 ^ (4 * ((d >> 2) & 3));
                float r0 = fmaxf(a0[i], 0.f), r1 = fmaxf(a1[i], 0.f);
                ((unsigned*)&ktc[d][0])[c] = pk2(r0 * c0,  r1 * c1);
                ((unsigned*)&kts[d][0])[c] = pk2(r0 * s0v, r1 * s1v);
            }
        } else {
            float4 v0q = *(const float4*)&rawV[it][r][dq];
            float4 v1q = *(const float4*)&rawV[it][r + 1][dq];
            float a0[4] = {v0q.x, v0q.y, v0q.z, v0q.w};
            float a1[4] = {v1q.x, v1q.y, v1q.z, v1q.w};
            #pragma unroll
            for (int i = 0; i < 4; ++i) {
                const int d = dq + i;
                const int c = g2 ^ (4 * ((d >> 2) & 3));
                ((unsigned*)&vtt[d][0])[c] = pk2(a0[i], a1[i]);
            }
        }
    };

    #pragma unroll
    for (int it = 0; it < NIT; ++it) {
        // wait ONLY for tile it (first 2*(it+1) ops) — rest stay in flight
        switch (it) {
            case 0: asm volatile("s_waitcnt vmcnt(14)" ::: "memory"); break;
            case 1: asm volatile("s_waitcnt vmcnt(12)" ::: "memory"); break;
            case 2: asm volatile("s_waitcnt vmcnt(10)" ::: "memory"); break;
            case 3: asm volatile("s_waitcnt vmcnt(8)"  ::: "memory"); break;
            case 4: asm volatile("s_waitcnt vmcnt(6)"  ::: "memory"); break;
            case 5: asm volatile("s_waitcnt vmcnt(4)"  ::: "memory"); break;
            case 6: asm volatile("s_waitcnt vmcnt(2)"  ::: "memory"); break;
            default: asm volatile("s_waitcnt vmcnt(0)" ::: "memory"); break;
        }
        __builtin_amdgcn_sched_barrier(0);
        barrier_noflush();      // all waves confirmed tile it; transposed free

        TRANSFORM(it);
        barrier_noflush();      // transposed tiles ready

        const ushort (*ap)[LPADT] = (w < 4) ? ktc : kts;
        const int ca = (kgrp * 4) ^ (4 * ((d0 >> 2) & 3));
        bf16x8v a = *(const bf16x8v*)&ap[d0][2 * ca];
        #pragma unroll
        for (int nt = 0; nt < 4; ++nt) {
            const int dn = nt * 16 + frow;
            const int cb = (kgrp * 4) ^ (4 * ((dn >> 2) & 3));
            bf16x8v b = *(const bf16x8v*)&vtt[dn][2 * cb];
            acc[nt] = mfma16(a, b, acc[nt]);
        }
        acc[4] = mfma16(a, onef, acc[4]);
    }

    // epilogue (C/D: col=lane&15, row=(lane>>4)*4+reg)
    const int fb = w * 16 + kgrp * 4;
    if (USE_ATOMIC) {
        float* pb = part + (size_t)bh * KVF;
        float* ps = part + KSBASE + bh * 128;
        #pragma unroll
        for (int nt = 0; nt < 4; ++nt)
            #pragma unroll
            for (int r = 0; r < 4; ++r)
                atomicAdd(&pb[(size_t)(fb + r) * DIM + nt * 16 + frow], acc[nt][r]);
        if (frow == 0)
            #pragma unroll
            for (int r = 0; r < 4; ++r) atomicAdd(&ps[fb + r], acc[4][r]);
    } else {
        float* pb = part + STRIDE_C * chunk + (size_t)bh * KVF;
        float* ps = part + STRIDE_C * chunk + KSBASE + bh * 128;
        #pragma unroll
        for (int nt = 0; nt < 4; ++nt)
            #pragma unroll
            for (int r = 0; r < 4; ++r)
                pb[(size_t)(fb + r) * DIM + nt * 16 + frow] = acc[nt][r];
        if (frow == 0)
            #pragma unroll
            for (int r = 0; r < 4; ++r) ps[fb + r] = acc[4][r];
    }
}

// ------- Reduce + pack into bf16 B-fragment layout for pass-2 MFMA -------
// bfrag[head][t][ks][lane][j]: B[k][n], k=ks*32+(lane>>4)*8+j, n=t*16+(lane&15)
// t=0..3: kv columns; t=4 col 0: ksum (denominator), other cols zero (memset).
template<int NC>
__global__ __launch_bounds__(256) void reduce_pack(
    const float* __restrict__ part, __hip_bfloat16* __restrict__ bfrag)
{
    size_t o = (size_t)blockIdx.x * 256 + threadIdx.x;
    float s = 0.f;
    #pragma unroll
    for (int c = 0; c < NC; ++c) s += part[(size_t)c * STRIDE_C + o];
    if (o < KSBASE) {
        int head = (int)(o >> 13);
        int r = (int)(o & 8191);
        int k = r >> 6, n = r & 63;
        int t = n >> 4, ks = k >> 5, lg = (k >> 3) & 3, j = k & 7;
        int lane = lg * 16 + (n & 15);
        bfrag[(size_t)head * FRAGH + (size_t)(((t * 4 + ks) * 64 + lane) * 8 + j)] =
            __float2bfloat16(s);
    } else {
        int r = (int)(o - KSBASE);
        int head = r >> 7, k = r & 127;
        int ks = k >> 5, lg = (k >> 3) & 3, j = k & 7;
        bfrag[(size_t)head * FRAGH + (size_t)(((16 + ks) * 64 + lg * 16) * 8 + j)] =
            __float2bfloat16(s);
    }
}

// ---------------- Pass 2: out = (q_cs @ kv_ext) * norm via MFMA ----------------
__global__ __launch_bounds__(256) void cosformer_out_mfma(
    const float* __restrict__ Q, const __hip_bfloat16* __restrict__ bfrag,
    float* __restrict__ out)
{
    __shared__ __hip_bfloat16 sb[FRAGH];   // 20 KB, fragment-linear
    const int head = blockIdx.x >> 3;
    const int tile = blockIdx.x & 7;
    const int tid  = threadIdx.x;

    {
        const float4* src = (const float4*)(bfrag + (size_t)head * FRAGH);
        float4* dst = (float4*)sb;
        #pragma unroll
        for (int i = 0; i < 5; ++i) dst[tid + 256 * i] = src[tid + 256 * i];
    }

    const int lane = tid & 63;
    const int w    = tid >> 6;
    const int mrow = lane & 15;
    const int kgrp = lane >> 4;

    const float* Qb = Q + (size_t)head * SEQ * DIM;
    float*       Ob = out + (size_t)head * SEQ * DIM;
    const int rowblk = tile * 512;

    float4 qb[2][4];
    #pragma unroll
    for (int m = 0; m < 2; ++m) {
        const float4* qr = (const float4*)(Qb + (size_t)(rowblk + w * 32 + m * 16 + mrow) * DIM);
        qb[m][0] = qr[kgrp * 2];
        qb[m][1] = qr[kgrp * 2 + 1];
        qb[m][2] = qr[8 + kgrp * 2];
        qb[m][3] = qr[8 + kgrp * 2 + 1];
    }

    barrier_noflush();   // sb staged; q loads stay in flight

    #pragma unroll
    for (int g = 0; g < 4; ++g) {
        const int base = rowblk + (g * 4 + w) * 32;

        bf16x8v af[2][4];
        #pragma unroll
        for (int m = 0; m < 2; ++m) {
            int arow = base + m * 16 + mrow;
            float ang = 1.5707963267948966f * (float)(arow + 1) / (float)SEQ;
            float sn, cn;
            __sincosf(ang, &sn, &cn);
            float crs = cn * 0.125f, srs = sn * 0.125f;
            float lo[8] = {qb[m][0].x, qb[m][0].y, qb[m][0].z, qb[m][0].w,
                           qb[m][1].x, qb[m][1].y, qb[m][1].z, qb[m][1].w};
            float hi[8] = {qb[m][2].x, qb[m][2].y, qb[m][2].z, qb[m][2].w,
                           qb[m][3].x, qb[m][3].y, qb[m][3].z, qb[m][3].w};
            #pragma unroll
            for (int j = 0; j < 8; ++j) {
                float rl = fmaxf(lo[j], 0.f);
                float rh = fmaxf(hi[j], 0.f);
                af[m][0][j] = (__bf16)(rl * crs);
                af[m][1][j] = (__bf16)(rh * crs);
                af[m][2][j] = (__bf16)(rl * srs);
                af[m][3][j] = (__bf16)(rh * srs);
            }
        }

        if (g < 3) {
            #pragma unroll
            for (int m = 0; m < 2; ++m) {
                const float4* qr = (const float4*)(Qb + (size_t)(rowblk + ((g + 1) * 4 + w) * 32 + m * 16 + mrow) * DIM);
                qb[m][0] = qr[kgrp * 2];
                qb[m][1] = qr[kgrp * 2 + 1];
                qb[m][2] = qr[8 + kgrp * 2];
                qb[m][3] = qr[8 + kgrp * 2 + 1];
            }
        }

        f32x4v acc[2][5];
        #pragma unroll
        for (int m = 0; m < 2; ++m)
            #pragma unroll
            for (int t = 0; t < 5; ++t)
                acc[m][t] = (f32x4v){0.f, 0.f, 0.f, 0.f};

        #pragma unroll
        for (int t = 0; t < 5; ++t)
            #pragma unroll
            for (int ks = 0; ks < 4; ++ks) {
                bf16x8v bf = *(const bf16x8v*)&sb[(size_t)(((t * 4 + ks) * 64 + lane) * 8)];
                acc[0][t] = mfma16(af[0][ks], bf, acc[0][t]);
                acc[1][t] = mfma16(af[1][ks], bf, acc[1][t]);
            }

        #pragma unroll
        for (int m = 0; m < 2; ++m) {
            #pragma unroll
            for (int r = 0; r < 4; ++r) {
                float den = __shfl(acc[m][4][r], lane & 48, 64);
                float invd = 1.0f / fmaxf(den, 1e-6f);
                int row = base + m * 16 + kgrp * 4 + r;
                float* op = Ob + (size_t)row * DIM + mrow;
                op[0]  = acc[m][0][r] * invd;
                op[16] = acc[m][1][r] * invd;
                op[32] = acc[m][2][r] * invd;
                op[48] = acc[m][3][r] * invd;
            }
        }
    }
}

extern "C" void kernel_launch(void* const* d_in, const int* in_sizes, int n_in,
                              void* d_out, int out_size, void* d_ws, size_t ws_size,
                              hipStream_t stream) {
    const float* Q = (const float*)d_in[0];
    const float* K = (const float*)d_in[1];
    const float* V = (const float*)d_in[2];
    float* out = (float*)d_out;
    float* ws  = (float*)d_ws;

    const size_t frag_bytes = (size_t)FRAGH * BHN * sizeof(__hip_bfloat16);
    const size_t need_full  = (size_t)NCHUNK * STRIDE_C * sizeof(float) + frag_bytes;

    if (ws_size >= need_full) {
        float* part = ws;
        __hip_bfloat16* bfrag = (__hip_bfloat16*)(ws + (size_t)NCHUNK * STRIDE_C);
        hipMemsetAsync(bfrag, 0, frag_bytes, stream);
        hipLaunchKernelGGL((cosformer_kv_mfma<0>), dim3(BHN * NCHUNK), dim3(512), 0, stream,
                           K, V, part);
        hipLaunchKernelGGL((reduce_pack<NCHUNK>), dim3((int)(STRIDE_C / 256)), dim3(256), 0, stream,
                           part, bfrag);
        hipLaunchKernelGGL(cosformer_out_mfma, dim3(BHN * 8), dim3(256), 0, stream,
                           Q, bfrag, out);
    } else {
        float* part = ws;
        __hip_bfloat16* bfrag = (__hip_bfloat16*)(ws + STRIDE_C);
        hipMemsetAsync(part, 0, STRIDE_C * sizeof(float), stream);
        hipMemsetAsync(bfrag, 0, frag_bytes, stream);
        hipLaunchKernelGGL((cosformer_kv_mfma<1>), dim3(BHN * NCHUNK), dim3(512), 0, stream,
                           K, V, part);
        hipLaunchKernelGGL((reduce_pack<1>), dim3((int)(STRIDE_C / 256)), dim3(256), 0, stream,
                           part, bfrag);
        hipLaunchKernelGGL(cosformer_out_mfma, dim3(BHN * 8), dim3(256), 0, stream,
                           Q, bfrag, out);
    }
}

// Round 16
// 64.980 us; speedup vs baseline: 1.3980x; 1.3980x over previous
//
#include <hip/hip_runtime.h>
#include <hip/hip_bf16.h>
#include <math.h>

#define BHN    64
#define SEQ    4096
#define DIM    64
#define NCHUNK 4
#define CHUNK  (SEQ / NCHUNK)        // 1024 rows per pass-1 block
#define KSTEP  64                    // s-rows staged per iteration
#define NIT    (CHUNK / KSTEP)       // 16 iterations
#define KVF    (128 * DIM)           // 8192 floats of kv per head
#define STRIDE_C ((size_t)BHN * KVF + (size_t)BHN * 128)   // 532480 floats
#define KSBASE ((size_t)BHN * KVF)   // 524288
#define FRAGH  10240                 // bf16 per head: 5 t * 4 ks * 64 lanes * 8 j
#define LPAD   72                    // LDS row pitch (ushorts)

typedef __bf16 bf16x8v __attribute__((ext_vector_type(8)));
typedef float  f32x4v  __attribute__((ext_vector_type(4)));

__device__ inline f32x4v mfma16(bf16x8v a, bf16x8v b, f32x4v c) {
    return __builtin_amdgcn_mfma_f32_16x16x32_bf16(a, b, c, 0, 0, 0);
}

__device__ inline unsigned pk2(float a, float b) {
    __hip_bfloat162 t(__float2bfloat16(a), __float2bfloat16(b));
    return *(unsigned*)&t;
}

// Raw workgroup barrier WITHOUT the compiler's vmcnt(0) drain.
__device__ __forceinline__ void barrier_noflush() {
    asm volatile("s_waitcnt lgkmcnt(0)" ::: "memory");
    __builtin_amdgcn_s_barrier();
    asm volatile("" ::: "memory");
}

// XOR swizzle on u32 column index (32 cols of s-pairs per d-row).
__device__ inline int swz(int d, int col) { return col ^ (4 * ((d >> 2) & 7)); }

// ------- Pass 1 (MFMA): partial kv/ksum per (head, chunk) -------
// kv[f][m] = sum_s k_cs[s][f] * V[s][m];  ksum[f] via ones-column N-tile.
// 512 threads = 8 waves; wave w owns feature tile w (cos tiles 0-3, sin 4-7).
// NIT=16; LDS double-buffer; 3 register load sets; raw barriers; phase
// rotation decorrelates concurrent blocks' address streams.
template<int USE_ATOMIC>
__global__ __launch_bounds__(512) void cosformer_kv_mfma(
    const float* __restrict__ K, const float* __restrict__ V,
    float* __restrict__ part)
{
    __shared__ ushort ktc[2][64][LPAD];   // relu(K)*cos, transposed [d][s], bf16
    __shared__ ushort kts[2][64][LPAD];   // relu(K)*sin
    __shared__ ushort vtt[2][64][LPAD];   // V, transposed [m][s], bf16

    const int bh    = blockIdx.x / NCHUNK;
    const int chunk = blockIdx.x % NCHUNK;
    const int row0  = chunk * CHUNK;
    const int ph    = (bh + chunk) & (NIT - 1);
    const float* Kb = K + (size_t)bh * SEQ * DIM;
    const float* Vb = V + (size_t)bh * SEQ * DIM;

    const int tid = threadIdx.x;
    const int dq = (tid & 15) * 4;   // d-block of 4
    const int g  = tid >> 4;         // s-pair index 0..31 (rows 2g, 2g+1)
    const int lane = tid & 63;
    const int w    = tid >> 6;       // 0..7
    const int frow = lane & 15;
    const int kgrp = lane >> 4;

    f32x4v acc[5];
    #pragma unroll
    for (int t = 0; t < 5; ++t) acc[t] = (f32x4v){0.f, 0.f, 0.f, 0.f};

    bf16x8v onef;
    #pragma unroll
    for (int j = 0; j < 8; ++j) onef[j] = (frow == 0) ? (__bf16)1.0f : (__bf16)0.0f;

    // three register staging sets (16 VGPR each)
    float4 sA[4], sB[4], sC[4];

    auto LOADS = [&](int it, float4* r) {
        const int tp = (it + ph) & (NIT - 1);          // physical tile
        const float* kp = Kb + (size_t)(row0 + tp * KSTEP + 2 * g) * DIM + dq;
        const float* vp = Vb + (size_t)(row0 + tp * KSTEP + 2 * g) * DIM + dq;
        r[0] = *(const float4*)kp;
        r[1] = *(const float4*)(kp + DIM);
        r[2] = *(const float4*)vp;
        r[3] = *(const float4*)(vp + DIM);
    };

    auto WRITES = [&](int it, const float4* r, int buf) {
        const int tp = (it + ph) & (NIT - 1);          // physical tile
        const int l0 = row0 + tp * KSTEP + 2 * g;
        const float CC = 1.5707963267948966f / (float)SEQ;
        float s0v, c0, s1v, c1;
        __sincosf(CC * (float)(l0 + 1), &s0v, &c0);
        __sincosf(CC * (float)(l0 + 2), &s1v, &c1);
        float k0[4] = {r[0].x, r[0].y, r[0].z, r[0].w};
        float k1[4] = {r[1].x, r[1].y, r[1].z, r[1].w};
        float v0[4] = {r[2].x, r[2].y, r[2].z, r[2].w};
        float v1[4] = {r[3].x, r[3].y, r[3].z, r[3].w};
        #pragma unroll
        for (int i = 0; i < 4; ++i) {
            const int d = dq + i;
            const int c = swz(d, g);
            float r0 = fmaxf(k0[i], 0.f), r1 = fmaxf(k1[i], 0.f);
            ((unsigned*)&ktc[buf][d][0])[c] = pk2(r0 * c0,  r1 * c1);
            ((unsigned*)&kts[buf][d][0])[c] = pk2(r0 * s0v, r1 * s1v);
            ((unsigned*)&vtt[buf][d][0])[c] = pk2(v0[i],    v1[i]);
        }
    };

    // set index for load/stage i is i%3 (A,B,C rotating)
    auto LOADS_SEL = [&](int it) {
        int sel = it % 3;
        if (sel == 0) LOADS(it, sA);
        else if (sel == 1) LOADS(it, sB);
        else LOADS(it, sC);
    };
    auto WRITES_SEL = [&](int it, int buf) {
        int sel = it % 3;
        if (sel == 0) WRITES(it, sA, buf);
        else if (sel == 1) WRITES(it, sB, buf);
        else WRITES(it, sC, buf);
    };

    // prologue: one cold stall (W0 waits on L0) while L1,L2 fly;
    // set A is freed by W0 and immediately reloaded with tile 3.
    LOADS_SEL(0);
    LOADS_SEL(1);
    LOADS_SEL(2);
    WRITES_SEL(0, 0);
    LOADS_SEL(3);
    barrier_noflush();

    const int d0 = (w & 3) * 16 + frow;

    #pragma unroll
    for (int it = 0; it < NIT; ++it) {
        const int buf = it & 1;
        const ushort (*ap)[LPAD] = (w < 4) ? ktc[buf] : kts[buf];
        const ushort (*bp)[LPAD] = vtt[buf];
        #pragma unroll
        for (int ks = 0; ks < 2; ++ks) {
            const int cb = ks * 16 + kgrp * 4;   // u32 col base (= s-offset/2)
            bf16x8v a = *(const bf16x8v*)&ap[d0][2 * swz(d0, cb)];
            #pragma unroll
            for (int nt = 0; nt < 4; ++nt) {
                const int dn = nt * 16 + frow;
                bf16x8v b = *(const bf16x8v*)&bp[dn][2 * swz(dn, cb)];
                acc[nt] = mfma16(a, b, acc[nt]);
            }
            acc[4] = mfma16(a, onef, acc[4]);
        }
        if (it + 1 < NIT) {
            WRITES_SEL(it + 1, buf ^ 1);
            if (it + 4 < NIT) LOADS_SEL(it + 4);
        }
        barrier_noflush();   // next buffer staged; readers of buf done
    }

    // epilogue (C/D: col=lane&15, row=(lane>>4)*4+reg)
    const int fb = w * 16 + kgrp * 4;
    if (USE_ATOMIC) {
        float* pb = part + (size_t)bh * KVF;
        float* ps = part + KSBASE + bh * 128;
        #pragma unroll
        for (int nt = 0; nt < 4; ++nt)
            #pragma unroll
            for (int r = 0; r < 4; ++r)
                atomicAdd(&pb[(size_t)(fb + r) * DIM + nt * 16 + frow], acc[nt][r]);
        if (frow == 0)
            #pragma unroll
            for (int r = 0; r < 4; ++r) atomicAdd(&ps[fb + r], acc[4][r]);
    } else {
        float* pb = part + STRIDE_C * chunk + (size_t)bh * KVF;
        float* ps = part + STRIDE_C * chunk + KSBASE + bh * 128;
        #pragma unroll
        for (int nt = 0; nt < 4; ++nt)
            #pragma unroll
            for (int r = 0; r < 4; ++r)
                pb[(size_t)(fb + r) * DIM + nt * 16 + frow] = acc[nt][r];
        if (frow == 0)
            #pragma unroll
            for (int r = 0; r < 4; ++r) ps[fb + r] = acc[4][r];
    }
}

// ------- Reduce + pack into bf16 B-fragment layout for pass-2 MFMA -------
// bfrag[head][t][ks][lane][j]: B[k][n], k=ks*32+(lane>>4)*8+j, n=t*16+(lane&15)
// t=0..3: kv columns; t=4 col 0: ksum (denominator), other cols zero (memset).
template<int NC>
__global__ __launch_bounds__(256) void reduce_pack(
    const float* __restrict__ part, __hip_bfloat16* __restrict__ bfrag)
{
    size_t o = (size_t)blockIdx.x * 256 + threadIdx.x;
    float s = 0.f;
    #pragma unroll
    for (int c = 0; c < NC; ++c) s += part[(size_t)c * STRIDE_C + o];
    if (o < KSBASE) {
        int head = (int)(o >> 13);
        int r = (int)(o & 8191);
        int k = r >> 6, n = r & 63;
        int t = n >> 4, ks = k >> 5, lg = (k >> 3) & 3, j = k & 7;
        int lane = lg * 16 + (n & 15);
        bfrag[(size_t)head * FRAGH + (size_t)(((t * 4 + ks) * 64 + lane) * 8 + j)] =
            __float2bfloat16(s);
    } else {
        int r = (int)(o - KSBASE);
        int head = r >> 7, k = r & 127;
        int ks = k >> 5, lg = (k >> 3) & 3, j = k & 7;
        bfrag[(size_t)head * FRAGH + (size_t)(((16 + ks) * 64 + lg * 16) * 8 + j)] =
            __float2bfloat16(s);
    }
}

// ---------------- Pass 2: out = (q_cs @ kv_ext) * norm via MFMA ----------------
__global__ __launch_bounds__(256) void cosformer_out_mfma(
    const float* __restrict__ Q, const __hip_bfloat16* __restrict__ bfrag,
    float* __restrict__ out)
{
    __shared__ __hip_bfloat16 sb[FRAGH];   // 20 KB, fragment-linear
    const int head = blockIdx.x >> 3;
    const int tile = blockIdx.x & 7;
    const int tid  = threadIdx.x;

    {
        const float4* src = (const float4*)(bfrag + (size_t)head * FRAGH);
        float4* dst = (float4*)sb;
        #pragma unroll
        for (int i = 0; i < 5; ++i) dst[tid + 256 * i] = src[tid + 256 * i];
    }

    const int lane = tid & 63;
    const int w    = tid >> 6;
    const int mrow = lane & 15;
    const int kgrp = lane >> 4;

    const float* Qb = Q + (size_t)head * SEQ * DIM;
    float*       Ob = out + (size_t)head * SEQ * DIM;
    const int rowblk = tile * 512;

    float4 qb[2][4];
    #pragma unroll
    for (int m = 0; m < 2; ++m) {
        const float4* qr = (const float4*)(Qb + (size_t)(rowblk + w * 32 + m * 16 + mrow) * DIM);
        qb[m][0] = qr[kgrp * 2];
        qb[m][1] = qr[kgrp * 2 + 1];
        qb[m][2] = qr[8 + kgrp * 2];
        qb[m][3] = qr[8 + kgrp * 2 + 1];
    }

    barrier_noflush();   // sb staged; q loads stay in flight

    #pragma unroll
    for (int g = 0; g < 4; ++g) {
        const int base = rowblk + (g * 4 + w) * 32;

        bf16x8v af[2][4];
        #pragma unroll
        for (int m = 0; m < 2; ++m) {
            int arow = base + m * 16 + mrow;
            float ang = 1.5707963267948966f * (float)(arow + 1) / (float)SEQ;
            float sn, cn;
            __sincosf(ang, &sn, &cn);
            float crs = cn * 0.125f, srs = sn * 0.125f;
            float lo[8] = {qb[m][0].x, qb[m][0].y, qb[m][0].z, qb[m][0].w,
                           qb[m][1].x, qb[m][1].y, qb[m][1].z, qb[m][1].w};
            float hi[8] = {qb[m][2].x, qb[m][2].y, qb[m][2].z, qb[m][2].w,
                           qb[m][3].x, qb[m][3].y, qb[m][3].z, qb[m][3].w};
            #pragma unroll
            for (int j = 0; j < 8; ++j) {
                float rl = fmaxf(lo[j], 0.f);
                float rh = fmaxf(hi[j], 0.f);
                af[m][0][j] = (__bf16)(rl * crs);
                af[m][1][j] = (__bf16)(rh * crs);
                af[m][2][j] = (__bf16)(rl * srs);
                af[m][3][j] = (__bf16)(rh * srs);
            }
        }

        if (g < 3) {
            #pragma unroll
            for (int m = 0; m < 2; ++m) {
                const float4* qr = (const float4*)(Qb + (size_t)(rowblk + ((g + 1) * 4 + w) * 32 + m * 16 + mrow) * DIM);
                qb[m][0] = qr[kgrp * 2];
                qb[m][1] = qr[kgrp * 2 + 1];
                qb[m][2] = qr[8 + kgrp * 2];
                qb[m][3] = qr[8 + kgrp * 2 + 1];
            }
        }

        f32x4v acc[2][5];
        #pragma unroll
        for (int m = 0; m < 2; ++m)
            #pragma unroll
            for (int t = 0; t < 5; ++t)
                acc[m][t] = (f32x4v){0.f, 0.f, 0.f, 0.f};

        #pragma unroll
        for (int t = 0; t < 5; ++t)
            #pragma unroll
            for (int ks = 0; ks < 4; ++ks) {
                bf16x8v bf = *(const bf16x8v*)&sb[(size_t)(((t * 4 + ks) * 64 + lane) * 8)];
                acc[0][t] = mfma16(af[0][ks], bf, acc[0][t]);
                acc[1][t] = mfma16(af[1][ks], bf, acc[1][t]);
            }

        #pragma unroll
        for (int m = 0; m < 2; ++m) {
            #pragma unroll
            for (int r = 0; r < 4; ++r) {
                float den = __shfl(acc[m][4][r], lane & 48, 64);
                float invd = 1.0f / fmaxf(den, 1e-6f);
                int row = base + m * 16 + kgrp * 4 + r;
                float* op = Ob + (size_t)row * DIM + mrow;
                op[0]  = acc[m][0][r] * invd;
                op[16] = acc[m][1][r] * invd;
                op[32] = acc[m][2][r] * invd;
                op[48] = acc[m][3][r] * invd;
            }
        }
    }
}

extern "C" void kernel_launch(void* const* d_in, const int* in_sizes, int n_in,
                              void* d_out, int out_size, void* d_ws, size_t ws_size,
                              hipStream_t stream) {
    const float* Q = (const float*)d_in[0];
    const float* K = (const float*)d_in[1];
    const float* V = (const float*)d_in[2];
    float* out = (float*)d_out;
    float* ws  = (float*)d_ws;

    const size_t frag_bytes = (size_t)FRAGH * BHN * sizeof(__hip_bfloat16);
    const size_t need_full  = (size_t)NCHUNK * STRIDE_C * sizeof(float) + frag_bytes;

    if (ws_size >= need_full) {
        float* part = ws;
        __hip_bfloat16* bfrag = (__hip_bfloat16*)(ws + (size_t)NCHUNK * STRIDE_C);
        hipMemsetAsync(bfrag, 0, frag_bytes, stream);
        hipLaunchKernelGGL((cosformer_kv_mfma<0>), dim3(BHN * NCHUNK), dim3(512), 0, stream,
                           K, V, part);
        hipLaunchKernelGGL((reduce_pack<NCHUNK>), dim3((int)(STRIDE_C / 256)), dim3(256), 0, stream,
                           part, bfrag);
        hipLaunchKernelGGL(cosformer_out_mfma, dim3(BHN * 8), dim3(256), 0, stream,
                           Q, bfrag, out);
    } else {
        float* part = ws;
        __hip_bfloat16* bfrag = (__hip_bfloat16*)(ws + STRIDE_C);
        hipMemsetAsync(part, 0, STRIDE_C * sizeof(float), stream);
        hipMemsetAsync(bfrag, 0, frag_bytes, stream);
        hipLaunchKernelGGL((cosformer_kv_mfma<1>), dim3(BHN * NCHUNK), dim3(512), 0, stream,
                           K, V, part);
        hipLaunchKernelGGL((reduce_pack<1>), dim3((int)(STRIDE_C / 256)), dim3(256), 0, stream,
                           part, bfrag);
        hipLaunchKernelGGL(cosformer_out_mfma, dim3(BHN * 8), dim3(256), 0, stream,
                           Q, bfrag, out);
    }
}